// Round 11
// baseline (16173.773 us; speedup 1.0000x reference)
//
#include <hip/hip_runtime.h>
#include <hip/hip_bf16.h>

typedef unsigned short u16;
typedef unsigned int u32;
typedef unsigned long long u64;
typedef __fp16 f16x2 __attribute__((ext_vector_type(2)));
typedef int i32x4 __attribute__((ext_vector_type(4)));

// ---------- sizes ----------
#define T_  8192
#define F_  1024
#define H_  2048
#define G_  8192   // 4*H

#define NREG  4     // replicated exchange regions
#define DSLOT 4     // ring depth (dataflow skew bound 2; 4 for margin)

// ws layout (bytes). Total ~176 MB.
#define WS_XG    0                    // bf16 [T][G]          134217728
#define WS_ABF   134217728ull         // bf16 [T][F]           16777216
#define WS_WBF   150994944ull         // bf16 [G][F]           16777216
#define WS_HX    167772160ull         // u32 [4][4][2048]        131072
#define WS_PART  168296448ull         // f32 [T][256]           8388608

static __device__ __forceinline__ float bf2f(u16 u) {
    union { u32 i; float f; } x; x.i = ((u32)u) << 16; return x.f;
}
static __device__ __forceinline__ u16 f2bf(float f) {
    union { float f; u32 u; } x; x.f = f;
    u32 r = (x.u + 0x7fffu + ((x.u >> 16) & 1u)) >> 16;
    return (u16)r;
}

// ---------- fp32 -> bf16 convert (4 elems/thread) ----------
__global__ void cvt4_kernel(const float* __restrict__ s, u16* __restrict__ d, int n4) {
    int i = blockIdx.x * 256 + threadIdx.x;
    if (i < n4) {
        float4 v = ((const float4*)s)[i];
        union { u16 h[4]; uint2 v2; } o;
        o.h[0] = f2bf(v.x); o.h[1] = f2bf(v.y); o.h[2] = f2bf(v.z); o.h[3] = f2bf(v.w);
        ((uint2*)d)[i] = o.v2;
    }
}

// ---------- x_gates GEMM: xg[t][g] = sum_f A[t][f]*W[g][f] + b_ih[g]+b_hh[g] ----------
__global__ __launch_bounds__(256) void gemm_xg_kernel(
    const u16* __restrict__ A, const u16* __restrict__ W,
    const float* __restrict__ b_ih, const float* __restrict__ b_hh,
    u16* __restrict__ xg)
{
    __shared__ u16 As[64][40];
    __shared__ u16 Ws[64][40];

    const int tb = blockIdx.y * 64;
    const int gb = blockIdx.x * 64;
    const int tid  = threadIdx.x;
    const int wave = tid >> 6;
    const int lane = tid & 63;
    const int m    = lane & 15;
    const int quad = lane >> 4;

    const int lrow = tid >> 2;
    const int lcol = (tid & 3) * 8;

    using frag  = __attribute__((ext_vector_type(8))) short;
    using f32x4 = __attribute__((ext_vector_type(4))) float;
    f32x4 acc[4] = {};

    for (int k0 = 0; k0 < F_; k0 += 32) {
        __syncthreads();
        *(uint4*)&As[lrow][lcol] = *(const uint4*)&A[(size_t)(tb + lrow) * F_ + k0 + lcol];
        *(uint4*)&Ws[lrow][lcol] = *(const uint4*)&W[(size_t)(gb + lrow) * F_ + k0 + lcol];
        __syncthreads();
        frag bfr = *(const frag*)&Ws[wave * 16 + m][quad * 8];
#pragma unroll
        for (int i = 0; i < 4; ++i) {
            frag afr = *(const frag*)&As[i * 16 + m][quad * 8];
            acc[i] = __builtin_amdgcn_mfma_f32_16x16x32_bf16(afr, bfr, acc[i], 0, 0, 0);
        }
    }
    const int g = gb + wave * 16 + m;
    const float bias = b_ih[g] + b_hh[g];
#pragma unroll
    for (int i = 0; i < 4; ++i)
#pragma unroll
        for (int r = 0; r < 4; ++r) {
            int t = tb + i * 16 + quad * 4 + r;
            xg[(size_t)t * G_ + g] = f2bf(acc[i][r] + bias);
        }
}

// ---------- persistent LSTM recurrence ----------
// EXACT round-10 structure (15.2 ms verified) except the poll loop.
// 256 blocks x 512 threads. Wave w owns hidden unit uu = b*8+w.
// Exchange word (u32) = [f16 h | tag16]; 4 regions x 4 slots x 2048 words.
// Publish: LDS-staged, wave 0 lanes 0..31 -> 4 replicas, 1 sector each.
// Round 11: PIPELINED 2-DEEP POLL. The old attempt loop was serialized
// (load -> vmcnt(0) -> check -> sleep -> load): sampling period = MALL RT
// (~600cy) + sleep ~= 780cy, so detect = visibility + ~760cy quantization.
// Now keep TWO loads in flight to the same address, staggered by s_sleep(3)
// (~192cy), checking the OLDEST via s_waitcnt vmcnt(1): sampling ~= 280cy,
// RT overlaps the stagger. Exit is wave-uniform (__all) -- correct because
// data-is-tag is monotone (a matched word never changes; reloads re-confirm).
// Hazards: sched_barrier(0) after every partial waitcnt (rule #18); final
// vmcnt(0) drain takes v0,v1 as asm INPUTS so the async-written registers
// stay live until the drain completes.
__global__ __launch_bounds__(512, 2) void lstm_rec_kernel(
    const float* __restrict__ Whh,   // [G][H] f32
    const u16*  __restrict__ xg,     // [T][G] bf16
    const float* __restrict__ Wout,  // [H]
    u32*  __restrict__ hx,           // [4][4][2048] u32, pre-filled 0xFF
    float* __restrict__ part)        // [T][256]
{
    __shared__ u32 hs2[2][H_ / 2];   // packed f16x2 (pair p = units 2p,2p+1), dbuf
    __shared__ float pl[2][8];       // per-wave output partials, dbuf
    __shared__ u32 hpub[8];          // per-wave packed publish words

    const int b   = blockIdx.x;
    const int tid = threadIdx.x;
    const int w   = tid >> 6;
    const int l   = tid & 63;
    const int uu  = b * 8 + w;          // hidden unit (wave-uniform)

    // weights (f16): wreg[r][kc] covers h-pair p = l + 64*kc of gate row r
    f16x2 wreg[4][16];
#pragma unroll
    for (int r = 0; r < 4; ++r) {
        const float* wrow = Whh + (size_t)(r * H_ + uu) * H_;
#pragma unroll
        for (int kc = 0; kc < 16; ++kc) {
            float2 v = *(const float2*)&wrow[2 * (l + 64 * kc)];
            wreg[r][kc] = __builtin_amdgcn_cvt_pkrtz(v.x, v.y);
        }
    }
    const float wout = Wout[uu];     // all lanes (wave-uniform)
    float c = 0.f;

    // h_{-1} = 0 lives in buffer 1 (iter t reads buf (t-1)&1, writes buf t&1)
    hs2[1][tid] = 0; hs2[1][tid + 512] = 0;
    __syncthreads();

    // xg for t=0: wave-uniform loads on ALL lanes (broadcast fetch)
    float xgi, xgf, xgg, xgo;
    {
        const u16* xr = &xg[uu];
        xgi = bf2f(xr[0]); xgf = bf2f(xr[2048]);
        xgg = bf2f(xr[4096]); xgo = bf2f(xr[6144]);
    }

    const u32* mybase = hx + (size_t)(b & (NREG - 1)) * DSLOT * 2048;

    for (int t = 0; t < T_; ++t) {
        const u32* hsrc = hs2[(t & 1) ^ 1];

        // deferred output-partial fold for step t-1 (off critical path)
        if (tid == 17 && t > 0) {
            const float* q = pl[(t - 1) & 1];
            part[(size_t)(t - 1) * 256 + b] =
                q[0] + q[1] + q[2] + q[3] + q[4] + q[5] + q[6] + q[7];
        }

        float a0 = 0.f, a1 = 0.f, a2 = 0.f, a3 = 0.f;
#pragma unroll
        for (int kc = 0; kc < 16; ++kc) {
            union { u32 u; f16x2 h; } hw;
            hw.u = hsrc[l + 64 * kc];
            a0 = __builtin_amdgcn_fdot2(wreg[0][kc], hw.h, a0, false);
            a1 = __builtin_amdgcn_fdot2(wreg[1][kc], hw.h, a1, false);
            a2 = __builtin_amdgcn_fdot2(wreg[2][kc], hw.h, a2, false);
            a3 = __builtin_amdgcn_fdot2(wreg[3][kc], hw.h, a3, false);
        }
#pragma unroll
        for (int off = 32; off >= 1; off >>= 1) {
            a0 += __shfl_xor(a0, off);
            a1 += __shfl_xor(a1, off);
            a2 += __shfl_xor(a2, off);
            a3 += __shfl_xor(a3, off);
        }

        // all-lane activation (bit-identical across lanes)
        float gi = a0 + xgi, gf = a1 + xgf, gg = a2 + xgg, go = a3 + xgo;
        float i_ = 1.f / (1.f + __expf(-gi));
        float f_ = 1.f / (1.f + __expf(-gf));
        float g_ = 1.f - 2.f / (__expf(2.f * gg) + 1.f);   // tanh
        float o_ = 1.f / (1.f + __expf(-go));
        c = fmaf(f_, c, i_ * g_);
        float th = 1.f - 2.f / (__expf(2.f * c) + 1.f);    // tanh
        float hval = o_ * th;

        const int slot = t & (DSLOT - 1);

        // stage packed word in LDS (1 write per wave)
        u32 word;
        {
            union { __fp16 hh; u16 us; } cv; cv.hh = (__fp16)hval;
            word = ((u32)cv.us << 16) | (u32)(t & 0xffff);
        }
        if (l == 0) hpub[w] = word;
        if (l == 17) pl[t & 1][w] = hval * wout;
        __syncthreads();   // B1: hpub complete (waves are balanced; ~100cy)

        // coalesced publish: wave 0, lanes 0..8*NREG-1 -> replica l>>3,
        // word 8b+(l&7) (one 32B sector per replica)
        if (w == 0 && l < 8 * NREG) {
            u32 v = hpub[l & 7];
            __hip_atomic_store(&hx[((size_t)(l >> 3) * DSLOT + slot) * 2048 + 8 * b + (l & 7)],
                               v, __ATOMIC_RELAXED, __HIP_MEMORY_SCOPE_AGENT);
        }

        // prefetch next step's xg (wave-uniform, in flight across the poll)
        float nxi = 0.f, nxf = 0.f, nxg = 0.f, nxo = 0.f;
        if (t + 1 < T_) {
            const u16* xr = &xg[(size_t)(t + 1) * G_ + uu];
            nxi = bf2f(xr[0]); nxf = bf2f(xr[2048]);
            nxg = bf2f(xr[4096]); nxo = bf2f(xr[6144]);
        }

        // pipelined 2-deep poll: thread tid owns units 4*tid..4*tid+3.
        // Two outstanding dwordx4 loads to the same address, staggered
        // s_sleep(3); check oldest via vmcnt(1). Wave-uniform exit (__all).
        {
            const u32* pb = mybase + (size_t)slot * 2048 + 4 * tid;
            const u32 te = (u32)(t & 0xffff);
            i32x4 v0, v1, vr;
            auto chk = [&](const i32x4& v) -> bool {
                return (((u32)v.x & 0xffffu) == te) & (((u32)v.y & 0xffffu) == te) &
                       (((u32)v.z & 0xffffu) == te) & (((u32)v.w & 0xffffu) == te);
            };
            asm volatile("global_load_dwordx4 %0, %1, off sc0 sc1"
                         : "=v"(v0) : "v"(pb) : "memory");
            __builtin_amdgcn_s_sleep(3);
            asm volatile("global_load_dwordx4 %0, %1, off sc0 sc1"
                         : "=v"(v1) : "v"(pb) : "memory");
            for (;;) {
                asm volatile("s_waitcnt vmcnt(1)" ::: "memory");
                __builtin_amdgcn_sched_barrier(0);
                if (__all((int)chk(v0))) { vr = v0; break; }
                asm volatile("global_load_dwordx4 %0, %1, off sc0 sc1"
                             : "=v"(v0) : "v"(pb) : "memory");
                __builtin_amdgcn_s_sleep(3);
                asm volatile("s_waitcnt vmcnt(1)" ::: "memory");
                __builtin_amdgcn_sched_barrier(0);
                if (__all((int)chk(v1))) { vr = v1; break; }
                asm volatile("global_load_dwordx4 %0, %1, off sc0 sc1"
                             : "=v"(v1) : "v"(pb) : "memory");
                __builtin_amdgcn_s_sleep(3);
            }
            // drain the still-in-flight load; v0/v1 as INPUTS keep their
            // registers live (async write target) until the drain completes
            asm volatile("s_waitcnt vmcnt(0)" :: "v"(v0), "v"(v1) : "memory");
            __builtin_amdgcn_sched_barrier(0);

            u32* dst = hs2[t & 1];
            dst[2 * tid]     = (((u32)vr.x) >> 16) | (((u32)vr.y) & 0xffff0000u);
            dst[2 * tid + 1] = (((u32)vr.z) >> 16) | (((u32)vr.w) & 0xffff0000u);
        }
        xgi = nxi; xgf = nxf; xgg = nxg; xgo = nxo;
        __syncthreads();   // B2: hs2[t&1] + pl[t&1] ready for next step
    }

    if (tid == 17) {
        const float* q = pl[(T_ - 1) & 1];
        part[(size_t)(T_ - 1) * 256 + b] =
            q[0] + q[1] + q[2] + q[3] + q[4] + q[5] + q[6] + q[7];
    }
}

// ---------- final: out[t] = b_out + sum_b part[t][b] ----------
__global__ __launch_bounds__(256) void out_reduce_kernel(
    const float* __restrict__ part, const float* __restrict__ b_out,
    float* __restrict__ out)
{
    int t = blockIdx.x * 4 + (threadIdx.x >> 6);
    int l = threadIdx.x & 63;
    const float* p = &part[(size_t)t * 256];
    float s = p[l] + p[l + 64] + p[l + 128] + p[l + 192];
#pragma unroll
    for (int off = 32; off >= 1; off >>= 1) s += __shfl_down(s, off);
    if (l == 0) out[t] = s + b_out[0];
}

extern "C" void kernel_launch(void* const* d_in, const int* in_sizes, int n_in,
                              void* d_out, int out_size, void* d_ws, size_t ws_size,
                              hipStream_t stream) {
    const float* input = (const float*)d_in[0];
    const float* W_ih  = (const float*)d_in[1];
    const float* W_hh  = (const float*)d_in[2];
    const float* b_ih  = (const float*)d_in[3];
    const float* b_hh  = (const float*)d_in[4];
    const float* W_out = (const float*)d_in[5];
    const float* b_out = (const float*)d_in[6];
    float* out = (float*)d_out;

    char* ws = (char*)d_ws;
    u16*   xg   = (u16*)(ws + WS_XG);
    u16*   Abf  = (u16*)(ws + WS_ABF);
    u16*   Wbf  = (u16*)(ws + WS_WBF);
    u32*   hx   = (u32*)(ws + WS_HX);
    float* part = (float*)(ws + WS_PART);

    // tags init to 0xFFFF (never equals any t&0xffff for t in [0,8192))
    (void)hipMemsetAsync(hx, 0xFF, (size_t)NREG * DSLOT * 2048 * sizeof(u32), stream);

    const int n4 = (T_ * F_) / 4;
    cvt4_kernel<<<(n4 + 255) / 256, 256, 0, stream>>>(input, Abf, n4);
    cvt4_kernel<<<(G_ * F_ / 4 + 255) / 256, 256, 0, stream>>>(W_ih, Wbf, G_ * F_ / 4);

    gemm_xg_kernel<<<dim3(G_ / 64, T_ / 64), 256, 0, stream>>>(Abf, Wbf, b_ih, b_hh, xg);

    lstm_rec_kernel<<<256, 512, 0, stream>>>(W_hh, xg, W_out, hx, part);

    out_reduce_kernel<<<T_ / 4, 256, 0, stream>>>(part, b_out, out);
}

// Round 12
// 15524.165 us; speedup vs baseline: 1.0418x; 1.0418x over previous
//
#include <hip/hip_runtime.h>
#include <hip/hip_bf16.h>

typedef unsigned short u16;
typedef unsigned int u32;
typedef unsigned long long u64;
typedef __fp16 f16x2 __attribute__((ext_vector_type(2)));
typedef int i32x4 __attribute__((ext_vector_type(4)));

// ---------- sizes ----------
#define T_  8192
#define F_  1024
#define H_  2048
#define G_  8192   // 4*H

#define NREG  4     // replicated exchange regions
#define DSLOT 4     // ring depth (dataflow skew bound 2; 4 for margin)

// ws layout (bytes). Total ~176 MB.
#define WS_XG    0                    // bf16 [T][G]          134217728
#define WS_ABF   134217728ull         // bf16 [T][F]           16777216
#define WS_WBF   150994944ull         // bf16 [G][F]           16777216
#define WS_HX    167772160ull         // u32 [4][4][2048]        131072
#define WS_PART  168296448ull         // f32 [T][256]           8388608

static __device__ __forceinline__ float bf2f(u16 u) {
    union { u32 i; float f; } x; x.i = ((u32)u) << 16; return x.f;
}
static __device__ __forceinline__ u16 f2bf(float f) {
    union { float f; u32 u; } x; x.f = f;
    u32 r = (x.u + 0x7fffu + ((x.u >> 16) & 1u)) >> 16;
    return (u16)r;
}

// ---------- fp32 -> bf16 convert (4 elems/thread) ----------
__global__ void cvt4_kernel(const float* __restrict__ s, u16* __restrict__ d, int n4) {
    int i = blockIdx.x * 256 + threadIdx.x;
    if (i < n4) {
        float4 v = ((const float4*)s)[i];
        union { u16 h[4]; uint2 v2; } o;
        o.h[0] = f2bf(v.x); o.h[1] = f2bf(v.y); o.h[2] = f2bf(v.z); o.h[3] = f2bf(v.w);
        ((uint2*)d)[i] = o.v2;
    }
}

// ---------- x_gates GEMM: xg[t][g] = sum_f A[t][f]*W[g][f] + b_ih[g]+b_hh[g] ----------
__global__ __launch_bounds__(256) void gemm_xg_kernel(
    const u16* __restrict__ A, const u16* __restrict__ W,
    const float* __restrict__ b_ih, const float* __restrict__ b_hh,
    u16* __restrict__ xg)
{
    __shared__ u16 As[64][40];
    __shared__ u16 Ws[64][40];

    const int tb = blockIdx.y * 64;
    const int gb = blockIdx.x * 64;
    const int tid  = threadIdx.x;
    const int wave = tid >> 6;
    const int lane = tid & 63;
    const int m    = lane & 15;
    const int quad = lane >> 4;

    const int lrow = tid >> 2;
    const int lcol = (tid & 3) * 8;

    using frag  = __attribute__((ext_vector_type(8))) short;
    using f32x4 = __attribute__((ext_vector_type(4))) float;
    f32x4 acc[4] = {};

    for (int k0 = 0; k0 < F_; k0 += 32) {
        __syncthreads();
        *(uint4*)&As[lrow][lcol] = *(const uint4*)&A[(size_t)(tb + lrow) * F_ + k0 + lcol];
        *(uint4*)&Ws[lrow][lcol] = *(const uint4*)&W[(size_t)(gb + lrow) * F_ + k0 + lcol];
        __syncthreads();
        frag bfr = *(const frag*)&Ws[wave * 16 + m][quad * 8];
#pragma unroll
        for (int i = 0; i < 4; ++i) {
            frag afr = *(const frag*)&As[i * 16 + m][quad * 8];
            acc[i] = __builtin_amdgcn_mfma_f32_16x16x32_bf16(afr, bfr, acc[i], 0, 0, 0);
        }
    }
    const int g = gb + wave * 16 + m;
    const float bias = b_ih[g] + b_hh[g];
#pragma unroll
    for (int i = 0; i < 4; ++i)
#pragma unroll
        for (int r = 0; r < 4; ++r) {
            int t = tb + i * 16 + quad * 4 + r;
            xg[(size_t)t * G_ + g] = f2bf(acc[i][r] + bias);
        }
}

// ---------- persistent LSTM recurrence ----------
// VERIFIED BEST (round 10, 15.2 ms rec / 15.5 ms e2e). Exact R4 structure
// with NREG=4. 256 blocks x 512 threads. Wave w owns hidden unit uu = b*8+w.
// Exchange word (u32) = [f16 h | tag16]; 4 regions x 4 slots x 2048 words.
// Publish: per-wave word -> LDS (hpub), B1, wave 0 lanes 0..31 store -> 4
// replicas, one 32B sector each. Poll: ONE dwordx4 sc0 sc1 per attempt +
// exponential backoff (sleep 1,2,4 then 8).
// Falsification ledger (rounds 5-11): service waves (+48%), T14 split (null),
// calibrated schedule (null), publisher isolation (+66%), NREG 8->4 (null,
// kept for traffic), 2-deep pipelined poll (-4%). The residual ~4460 cy/step
// = VALU issue ~1700 (2 waves/SIMD) + one MALL visibility hop ~1000-1500 +
// detect ~300-600 + 2 barriers ~300-500: a latency floor of the serial
// 8192-step device-wide broadcast, not a bandwidth/compute roofline.
__global__ __launch_bounds__(512, 2) void lstm_rec_kernel(
    const float* __restrict__ Whh,   // [G][H] f32
    const u16*  __restrict__ xg,     // [T][G] bf16
    const float* __restrict__ Wout,  // [H]
    u32*  __restrict__ hx,           // [4][4][2048] u32, pre-filled 0xFF
    float* __restrict__ part)        // [T][256]
{
    __shared__ u32 hs2[2][H_ / 2];   // packed f16x2 (pair p = units 2p,2p+1), dbuf
    __shared__ float pl[2][8];       // per-wave output partials, dbuf
    __shared__ u32 hpub[8];          // per-wave packed publish words

    const int b   = blockIdx.x;
    const int tid = threadIdx.x;
    const int w   = tid >> 6;
    const int l   = tid & 63;
    const int uu  = b * 8 + w;          // hidden unit (wave-uniform)

    // weights (f16): wreg[r][kc] covers h-pair p = l + 64*kc of gate row r
    f16x2 wreg[4][16];
#pragma unroll
    for (int r = 0; r < 4; ++r) {
        const float* wrow = Whh + (size_t)(r * H_ + uu) * H_;
#pragma unroll
        for (int kc = 0; kc < 16; ++kc) {
            float2 v = *(const float2*)&wrow[2 * (l + 64 * kc)];
            wreg[r][kc] = __builtin_amdgcn_cvt_pkrtz(v.x, v.y);
        }
    }
    const float wout = Wout[uu];     // all lanes (wave-uniform)
    float c = 0.f;

    // h_{-1} = 0 lives in buffer 1 (iter t reads buf (t-1)&1, writes buf t&1)
    hs2[1][tid] = 0; hs2[1][tid + 512] = 0;
    __syncthreads();

    // xg for t=0: wave-uniform loads on ALL lanes (broadcast fetch)
    float xgi, xgf, xgg, xgo;
    {
        const u16* xr = &xg[uu];
        xgi = bf2f(xr[0]); xgf = bf2f(xr[2048]);
        xgg = bf2f(xr[4096]); xgo = bf2f(xr[6144]);
    }

    const u32* mybase = hx + (size_t)(b & (NREG - 1)) * DSLOT * 2048;

    for (int t = 0; t < T_; ++t) {
        const u32* hsrc = hs2[(t & 1) ^ 1];

        // deferred output-partial fold for step t-1 (off critical path)
        if (tid == 17 && t > 0) {
            const float* q = pl[(t - 1) & 1];
            part[(size_t)(t - 1) * 256 + b] =
                q[0] + q[1] + q[2] + q[3] + q[4] + q[5] + q[6] + q[7];
        }

        float a0 = 0.f, a1 = 0.f, a2 = 0.f, a3 = 0.f;
#pragma unroll
        for (int kc = 0; kc < 16; ++kc) {
            union { u32 u; f16x2 h; } hw;
            hw.u = hsrc[l + 64 * kc];
            a0 = __builtin_amdgcn_fdot2(wreg[0][kc], hw.h, a0, false);
            a1 = __builtin_amdgcn_fdot2(wreg[1][kc], hw.h, a1, false);
            a2 = __builtin_amdgcn_fdot2(wreg[2][kc], hw.h, a2, false);
            a3 = __builtin_amdgcn_fdot2(wreg[3][kc], hw.h, a3, false);
        }
#pragma unroll
        for (int off = 32; off >= 1; off >>= 1) {
            a0 += __shfl_xor(a0, off);
            a1 += __shfl_xor(a1, off);
            a2 += __shfl_xor(a2, off);
            a3 += __shfl_xor(a3, off);
        }

        // all-lane activation (bit-identical across lanes)
        float gi = a0 + xgi, gf = a1 + xgf, gg = a2 + xgg, go = a3 + xgo;
        float i_ = 1.f / (1.f + __expf(-gi));
        float f_ = 1.f / (1.f + __expf(-gf));
        float g_ = 1.f - 2.f / (__expf(2.f * gg) + 1.f);   // tanh
        float o_ = 1.f / (1.f + __expf(-go));
        c = fmaf(f_, c, i_ * g_);
        float th = 1.f - 2.f / (__expf(2.f * c) + 1.f);    // tanh
        float hval = o_ * th;

        const int slot = t & (DSLOT - 1);

        // stage packed word in LDS (1 write per wave)
        u32 word;
        {
            union { __fp16 hh; u16 us; } cv; cv.hh = (__fp16)hval;
            word = ((u32)cv.us << 16) | (u32)(t & 0xffff);
        }
        if (l == 0) hpub[w] = word;
        if (l == 17) pl[t & 1][w] = hval * wout;
        __syncthreads();   // B1: hpub complete (waves are balanced; ~100cy)

        // coalesced publish: wave 0, lanes 0..8*NREG-1 -> replica l>>3,
        // word 8b+(l&7) (one 32B sector per replica)
        if (w == 0 && l < 8 * NREG) {
            u32 v = hpub[l & 7];
            __hip_atomic_store(&hx[((size_t)(l >> 3) * DSLOT + slot) * 2048 + 8 * b + (l & 7)],
                               v, __ATOMIC_RELAXED, __HIP_MEMORY_SCOPE_AGENT);
        }

        // prefetch next step's xg (wave-uniform, in flight across the poll)
        float nxi = 0.f, nxf = 0.f, nxg = 0.f, nxo = 0.f;
        if (t + 1 < T_) {
            const u16* xr = &xg[(size_t)(t + 1) * G_ + uu];
            nxi = bf2f(xr[0]); nxf = bf2f(xr[2048]);
            nxg = bf2f(xr[4096]); nxo = bf2f(xr[6144]);
        }

        // poll: thread tid owns units 4*tid .. 4*tid+3 (one 16B load/attempt),
        // exponential backoff: sleep 1,2,4 then 8 (s_sleep needs an immediate)
        {
            const u32* pb = mybase + (size_t)slot * 2048 + 4 * tid;
            const u32 te = (u32)(t & 0xffff);
            i32x4 v;
            auto attempt = [&]() -> bool {
                asm volatile("global_load_dwordx4 %0, %1, off sc0 sc1\n\t"
                             "s_waitcnt vmcnt(0)"
                             : "=v"(v) : "v"(pb) : "memory");
                return (((u32)v.x & 0xffffu) == te) & (((u32)v.y & 0xffffu) == te) &
                       (((u32)v.z & 0xffffu) == te) & (((u32)v.w & 0xffffu) == te);
            };
            if (!attempt()) {
                __builtin_amdgcn_s_sleep(1);
                if (!attempt()) {
                    __builtin_amdgcn_s_sleep(2);
                    if (!attempt()) {
                        __builtin_amdgcn_s_sleep(4);
                        while (!attempt()) __builtin_amdgcn_s_sleep(8);
                    }
                }
            }
            u32* dst = hs2[t & 1];
            dst[2 * tid]     = (((u32)v.x) >> 16) | (((u32)v.y) & 0xffff0000u);
            dst[2 * tid + 1] = (((u32)v.z) >> 16) | (((u32)v.w) & 0xffff0000u);
        }
        xgi = nxi; xgf = nxf; xgg = nxg; xgo = nxo;
        __syncthreads();   // B2: hs2[t&1] + pl[t&1] ready for next step
    }

    if (tid == 17) {
        const float* q = pl[(T_ - 1) & 1];
        part[(size_t)(T_ - 1) * 256 + b] =
            q[0] + q[1] + q[2] + q[3] + q[4] + q[5] + q[6] + q[7];
    }
}

// ---------- final: out[t] = b_out + sum_b part[t][b] ----------
__global__ __launch_bounds__(256) void out_reduce_kernel(
    const float* __restrict__ part, const float* __restrict__ b_out,
    float* __restrict__ out)
{
    int t = blockIdx.x * 4 + (threadIdx.x >> 6);
    int l = threadIdx.x & 63;
    const float* p = &part[(size_t)t * 256];
    float s = p[l] + p[l + 64] + p[l + 128] + p[l + 192];
#pragma unroll
    for (int off = 32; off >= 1; off >>= 1) s += __shfl_down(s, off);
    if (l == 0) out[t] = s + b_out[0];
}

extern "C" void kernel_launch(void* const* d_in, const int* in_sizes, int n_in,
                              void* d_out, int out_size, void* d_ws, size_t ws_size,
                              hipStream_t stream) {
    const float* input = (const float*)d_in[0];
    const float* W_ih  = (const float*)d_in[1];
    const float* W_hh  = (const float*)d_in[2];
    const float* b_ih  = (const float*)d_in[3];
    const float* b_hh  = (const float*)d_in[4];
    const float* W_out = (const float*)d_in[5];
    const float* b_out = (const float*)d_in[6];
    float* out = (float*)d_out;

    char* ws = (char*)d_ws;
    u16*   xg   = (u16*)(ws + WS_XG);
    u16*   Abf  = (u16*)(ws + WS_ABF);
    u16*   Wbf  = (u16*)(ws + WS_WBF);
    u32*   hx   = (u32*)(ws + WS_HX);
    float* part = (float*)(ws + WS_PART);

    // tags init to 0xFFFF (never equals any t&0xffff for t in [0,8192))
    (void)hipMemsetAsync(hx, 0xFF, (size_t)NREG * DSLOT * 2048 * sizeof(u32), stream);

    const int n4 = (T_ * F_) / 4;
    cvt4_kernel<<<(n4 + 255) / 256, 256, 0, stream>>>(input, Abf, n4);
    cvt4_kernel<<<(G_ * F_ / 4 + 255) / 256, 256, 0, stream>>>(W_ih, Wbf, G_ * F_ / 4);

    gemm_xg_kernel<<<dim3(G_ / 64, T_ / 64), 256, 0, stream>>>(Abf, Wbf, b_ih, b_hh, xg);

    lstm_rec_kernel<<<256, 512, 0, stream>>>(W_hh, xg, W_out, hx, part);

    out_reduce_kernel<<<T_ / 4, 256, 0, stream>>>(part, b_out, out);
}